// Round 2
// baseline (7929.252 us; speedup 1.0000x reference)
//
#include <hip/hip_runtime.h>
#include <hip/hip_bf16.h>

// Sizes
#define ICN 512
#define OCN 512
#define HN  128
#define WN  128
// Padded "pixel space" layout for the 4 phase outputs of the transposed conv:
// each phase stores a (<=129 x <=129) grid at pix = (a+1)*RS + (b+1) inside an
// RS x RS padded grid, with per-oc stride NPAD (multiple of 128 for future GEMM).
#define RS   136
#define NPAD 18560   // 145*128 >= RS*RS = 18496

// ---------------- demod: coef[oc] = scale * rsqrt(scale^2 * sum(w^2) + eps) ----
__global__ __launch_bounds__(256) void demod_k(const float* __restrict__ w,
                                               float* __restrict__ coef) {
  const int oc = blockIdx.x;
  const float* wp = w + (size_t)oc * ICN * 9;
  float s = 0.f;
  for (int i = threadIdx.x; i < ICN * 9; i += 256) { float v = wp[i]; s += v * v; }
#pragma unroll
  for (int o = 32; o > 0; o >>= 1) s += __shfl_down(s, o, 64);
  __shared__ float red[4];
  if ((threadIdx.x & 63) == 0) red[threadIdx.x >> 6] = s;
  __syncthreads();
  if (threadIdx.x == 0) {
    float t = red[0] + red[1] + red[2] + red[3];
    const float scale2 = 1.0f / 4608.0f;  // (1/sqrt(IC*K*K))^2
    coef[oc] = sqrtf(scale2) * rsqrtf(scale2 * t + 1e-8f);
  }
}

// ---------------- stage 1: polyphase transposed conv ---------------------------
// up[2a+py][2b+px] = sum_ic sum_t x[a-dy_t][b-dx_t] * w[oc][ic][wy_t][wx_t]
// PHASE: 0=(even y,even x) 1=(even,odd) 2=(odd,even) 3=(odd,odd)
template <int PHASE>
__global__ __launch_bounds__(256) void up_k(const float* __restrict__ x,
                                            const float* __restrict__ w,
                                            const float* __restrict__ coef,
                                            __hip_bfloat16* __restrict__ C) {
  constexpr int NT = (PHASE == 0) ? 4 : ((PHASE == 3) ? 1 : 2);
  constexpr int DYs[4][4] = {{0,0,1,1},{0,1,0,0},{0,0,0,0},{0,0,0,0}};
  constexpr int DXs[4][4] = {{0,1,0,1},{0,0,0,0},{0,1,0,0},{0,0,0,0}};
  constexpr int WIs[4][4] = {{0,2,6,8},{1,7,0,0},{3,5,0,0},{4,0,0,0}};
  constexpr int BMAX = (PHASE == 0 || PHASE == 2) ? 129 : 128;  // valid cols

  const int b = threadIdx.x;
  if (b >= BMAX) return;
  const int a   = blockIdx.x;       // row index within phase
  const int ocb = blockIdx.y * 32;  // oc block of 32

  int   xoff[NT];
  float xm[NT];
#pragma unroll
  for (int t = 0; t < NT; t++) {
    int  ry = a - DYs[PHASE][t], rx = b - DXs[PHASE][t];
    bool v  = (ry >= 0) && (ry < HN) && (rx >= 0) && (rx < WN);
    xoff[t] = v ? (ry * WN + rx) : 0;
    xm[t]   = v ? 1.f : 0.f;
  }

  float acc[32];
#pragma unroll
  for (int o = 0; o < 32; o++) acc[o] = 0.f;

  for (int ic = 0; ic < ICN; ic++) {
    float xv[NT];
#pragma unroll
    for (int t = 0; t < NT; t++) xv[t] = x[ic * (HN * WN) + xoff[t]] * xm[t];
    const float* wp = w + ((size_t)ocb * ICN + ic) * 9;
#pragma unroll
    for (int o = 0; o < 32; o++) {
      const float* wo = wp + (size_t)o * ICN * 9;  // uniform -> scalar loads
      float s = 0.f;
#pragma unroll
      for (int t = 0; t < NT; t++) s += xv[t] * wo[WIs[PHASE][t]];
      acc[o] += s;
    }
  }

  const int pix = (a + 1) * RS + (b + 1);
#pragma unroll
  for (int o = 0; o < 32; o++) {
    float v = coef[ocb + o] * acc[o];
    C[((size_t)(PHASE * OCN + ocb + o)) * NPAD + pix] = __float2bfloat16(v);
  }
}

// ---------------- stage 2: depthwise 4x4 blur, pad 1 ---------------------------
// out[m][n] = sum_{i,j} (b_i/4)(b_j/4) * up[m-1+i][n-1+j], b={1,3,3,1}
__global__ __launch_bounds__(256) void blur_k(const __hip_bfloat16* __restrict__ C,
                                              float* __restrict__ out) {
  const int n  = threadIdx.x;  // 0..255
  const int m  = blockIdx.x;   // 0..255
  const int oc = blockIdx.y;   // 0..511
  const float cf[4] = {0.25f, 0.75f, 0.75f, 0.25f};

  float acc = 0.f;
#pragma unroll
  for (int i = 0; i < 4; i++) {
    int u = m - 1 + i;
    if (u < 0 || u > 256) continue;
    int py = u & 1, aa = u >> 1;
    float rowacc = 0.f;
#pragma unroll
    for (int j = 0; j < 4; j++) {
      int v = n - 1 + j;
      if (v < 0 || v > 256) continue;
      int px = v & 1, bb = v >> 1;
      const __hip_bfloat16* Cp =
          C + ((size_t)((py * 2 + px) * OCN + oc)) * NPAD + (aa + 1) * RS + (bb + 1);
      rowacc += cf[j] * __bfloat162float(*Cp);
    }
    acc += cf[i] * rowacc;
  }
  out[((size_t)oc * 256 + m) * 256 + n] = acc;
}

extern "C" void kernel_launch(void* const* d_in, const int* in_sizes, int n_in,
                              void* d_out, int out_size, void* d_ws, size_t ws_size,
                              hipStream_t stream) {
  const float* x = (const float*)d_in[0];
  const float* w = (const float*)d_in[1];
  float* out = (float*)d_out;

  // ws layout: [0,2048) coef (512 f32); [2048, 2048 + 4*512*18560*2) phase outputs bf16
  float* coef = (float*)d_ws;
  __hip_bfloat16* C = (__hip_bfloat16*)((char*)d_ws + 2048);

  demod_k<<<512, 256, 0, stream>>>(w, coef);
  // phase grids: rows = 129 for even-y, 128 for odd-y; block covers cols (+guard)
  up_k<0><<<dim3(129, 16), 192, 0, stream>>>(x, w, coef, C);
  up_k<1><<<dim3(129, 16), 128, 0, stream>>>(x, w, coef, C);
  up_k<2><<<dim3(128, 16), 192, 0, stream>>>(x, w, coef, C);
  up_k<3><<<dim3(128, 16), 128, 0, stream>>>(x, w, coef, C);
  blur_k<<<dim3(256, 512), 256, 0, stream>>>(C, out);
}

// Round 5
// 581.810 us; speedup vs baseline: 13.6286x; 13.6286x over previous
//
#include <hip/hip_runtime.h>
#include <hip/hip_bf16.h>

#define ICN 512
#define OCN 512
#define RS    136      // padded pixel-plane row stride (cols)
#define PROWS 130      // padded pixel-plane rows with data/halo
#define NROW  17792    // GEMM N = 139*128 >= 130*136=17680; also C plane stride
#define GUARD 144      // zero guard rows in front of XPT (max shift 137)
#define XROWS 17936    // GUARD + NROW

typedef __attribute__((ext_vector_type(8))) short short8;
typedef __attribute__((ext_vector_type(4))) float f32x4;

__device__ __forceinline__ void gload_lds16(const void* g, void* l) {
  __builtin_amdgcn_global_load_lds(
      (const __attribute__((address_space(1))) void*)g,
      (__attribute__((address_space(3))) void*)l, 16, 0, 0);
}

// ---- fused demod + weight pack: AP[tp][oc][ic] = coef[oc]*w[oc][ic][widx(tp)] ----
__global__ __launch_bounds__(256) void wprep_k(const float* __restrict__ w,
                                               __hip_bfloat16* __restrict__ AP) {
  constexpr int WIDX[9] = {0, 2, 6, 8, 1, 7, 3, 5, 4};  // tap -> ky*3+kx
  const int oc = blockIdx.x;
  const int tid = threadIdx.x, lane = tid & 63, wv = tid >> 6;

  float v[2][9];
  float s = 0.f;
#pragma unroll
  for (int rep = 0; rep < 2; ++rep) {
    const int ic = tid + rep * 256;
    const float* wp = w + ((size_t)oc * ICN + ic) * 9;
#pragma unroll
    for (int j = 0; j < 9; ++j) { v[rep][j] = wp[j]; s += wp[j] * wp[j]; }
  }
#pragma unroll
  for (int o = 32; o > 0; o >>= 1) s += __shfl_down(s, o, 64);
  __shared__ float red[4];
  if (lane == 0) red[wv] = s;
  __syncthreads();
  const float tot = red[0] + red[1] + red[2] + red[3];
  const float scale2 = 1.0f / 4608.0f;
  const float c = sqrtf(scale2) * rsqrtf(scale2 * tot + 1e-8f);

#pragma unroll
  for (int rep = 0; rep < 2; ++rep) {
    const int ic = tid + rep * 256;
#pragma unroll
    for (int tp = 0; tp < 9; ++tp)
      AP[((size_t)tp * OCN + oc) * ICN + ic] = __float2bfloat16(c * v[rep][WIDX[tp]]);
  }
}

// ---- x -> bf16 transposed padded pixel space: XPT[row][ic], row = GUARD + py*RS + px
__global__ __launch_bounds__(256) void packx_k(const float* __restrict__ x,
                                               unsigned int* __restrict__ XP32) {
  const int tid = threadIdx.x;
  int row = blockIdx.x * 16;
  for (int r = 0; r < 16; ++r, ++row) {
    float v0 = 0.f, v1 = 0.f;
    if (row >= GUARD) {
      const int p = row - GUARD;           // 0..NROW-1
      const int py = p / RS, px = p - py * RS;
      const int yy = py - 1, xx = px - 1;
      if (yy >= 0 && yy < 128 && xx >= 0 && xx < 128) {
        const int o = yy * 128 + xx;
        v0 = x[(size_t)(2 * tid) * 16384 + o];
        v1 = x[(size_t)(2 * tid + 1) * 16384 + o];
      }
    }
    union { __hip_bfloat16 h[2]; unsigned int u; } cv;
    cv.h[0] = __float2bfloat16(v0);
    cv.h[1] = __float2bfloat16(v1);
    XP32[(size_t)row * 256 + tid] = cv.u;
  }
}

// ---- MFMA implicit GEMM: C[ph][oc][n] = sum_t sum_ic AP[tp][oc][ic]*XPT[n-sh][ic]
__global__ __launch_bounds__(256) void gemm_k(const __hip_bfloat16* __restrict__ AP,
                                              const __hip_bfloat16* __restrict__ XPT,
                                              __hip_bfloat16* __restrict__ C) {
  constexpr int NTt[4]   = {4, 2, 2, 1};
  constexpr int TPO[4]   = {0, 4, 6, 8};
  constexpr int SHIFT[9] = {0, 1, 136, 137, 0, 136, 0, 1, 0};

  const int n0 = blockIdx.x * 128, oc0 = blockIdx.y * 128, ph = blockIdx.z;
  const int tid = threadIdx.x, lane = tid & 63, wv = tid >> 6;
  const int wr = wv >> 1, wc = wv & 1;

  __shared__ __align__(16) __hip_bfloat16 lA[128 * 32];
  __shared__ __align__(16) __hip_bfloat16 lB[128 * 32];

  const int srow = tid >> 2;          // 0..63 (staging row)
  const int scol = (tid & 3) * 8;     // staging col (elems)
  __hip_bfloat16* ldA0 = &lA[wv * 512];
  __hip_bfloat16* ldA1 = &lA[wv * 512 + 2048];
  __hip_bfloat16* ldB0 = &lB[wv * 512];
  __hip_bfloat16* ldB1 = &lB[wv * 512 + 2048];

  f32x4 acc[4][4];
#pragma unroll
  for (int m = 0; m < 4; ++m)
#pragma unroll
    for (int n = 0; n < 4; ++n) acc[m][n] = (f32x4){0.f, 0.f, 0.f, 0.f};

  const int ntaps = NTt[ph];
  for (int t = 0; t < ntaps; ++t) {
    const int tp = TPO[ph] + t;
    const __hip_bfloat16* Ab = AP + (size_t)tp * (ICN * OCN) + (size_t)oc0 * ICN;
    const __hip_bfloat16* Bb = XPT + (size_t)(GUARD + n0 - SHIFT[tp]) * ICN;
    for (int ks = 0; ks < 16; ++ks) {
      const int kc = ks * 32 + scol;
      gload_lds16(Ab + (size_t)srow * ICN + kc, ldA0);
      gload_lds16(Ab + (size_t)(srow + 64) * ICN + kc, ldA1);
      gload_lds16(Bb + (size_t)srow * ICN + kc, ldB0);
      gload_lds16(Bb + (size_t)(srow + 64) * ICN + kc, ldB1);
      __syncthreads();
      short8 af[4], bfr[4];
#pragma unroll
      for (int m = 0; m < 4; ++m)
        af[m] = *(const short8*)&lA[(wr * 64 + m * 16 + (lane & 15)) * 32 + (lane >> 4) * 8];
#pragma unroll
      for (int n = 0; n < 4; ++n)
        bfr[n] = *(const short8*)&lB[(wc * 64 + n * 16 + (lane & 15)) * 32 + (lane >> 4) * 8];
#pragma unroll
      for (int m = 0; m < 4; ++m)
#pragma unroll
        for (int n = 0; n < 4; ++n)
          acc[m][n] = __builtin_amdgcn_mfma_f32_16x16x32_bf16(af[m], bfr[n], acc[m][n], 0, 0, 0);
      __syncthreads();
    }
  }

  // epilogue: D col = lane&15, row = (lane>>4)*4 + r
  const int lr = (lane >> 4) * 4, lc = lane & 15;
#pragma unroll
  for (int m = 0; m < 4; ++m)
#pragma unroll
    for (int n = 0; n < 4; ++n)
#pragma unroll
      for (int r = 0; r < 4; ++r) {
        const int row = oc0 + wr * 64 + m * 16 + lr + r;
        const int col = n0 + wc * 64 + n * 16 + lc;
        C[((size_t)(ph * OCN + row)) * NROW + col] = __float2bfloat16(acc[m][n][r]);
      }
}

// ---- depthwise 4x4 blur, pad 1 ----
__global__ __launch_bounds__(256) void blur_k(const __hip_bfloat16* __restrict__ C,
                                              float* __restrict__ out) {
  const int n  = threadIdx.x;  // 0..255
  const int m  = blockIdx.x;   // 0..255
  const int oc = blockIdx.y;   // 0..511
  const float cf[4] = {0.25f, 0.75f, 0.75f, 0.25f};

  float acc = 0.f;
#pragma unroll
  for (int i = 0; i < 4; i++) {
    int u = m - 1 + i;
    if (u < 0 || u > 256) continue;
    int py = u & 1, aa = u >> 1;
    float rowacc = 0.f;
#pragma unroll
    for (int j = 0; j < 4; j++) {
      int v = n - 1 + j;
      if (v < 0 || v > 256) continue;
      int px = v & 1, bb = v >> 1;
      const __hip_bfloat16* Cp =
          C + ((size_t)((py * 2 + px) * OCN + oc)) * NROW + (aa + 1) * RS + (bb + 1);
      rowacc += cf[j] * __bfloat162float(*Cp);
    }
    acc += cf[i] * rowacc;
  }
  out[((size_t)oc * 256 + m) * 256 + n] = acc;
}

extern "C" void kernel_launch(void* const* d_in, const int* in_sizes, int n_in,
                              void* d_out, int out_size, void* d_ws, size_t ws_size,
                              hipStream_t stream) {
  const float* x = (const float*)d_in[0];
  const float* w = (const float*)d_in[1];
  float* out = (float*)d_out;

  // ws layout (bytes):
  //   AP : 9*512*512*2   = 4,718,592    @ 0
  //   XPT: 17936*512*2   = 18,366,464   @ 4,718,592
  //   C  : 4*512*17792*2 = 72,876,032   @ 23,085,056   (total ~96.0 MB)
  __hip_bfloat16* AP  = (__hip_bfloat16*)d_ws;
  __hip_bfloat16* XPT = (__hip_bfloat16*)((char*)d_ws + 4718592);
  __hip_bfloat16* C   = (__hip_bfloat16*)((char*)d_ws + 23085056);

  wprep_k<<<512, 256, 0, stream>>>(w, AP);
  packx_k<<<XROWS / 16, 256, 0, stream>>>(x, (unsigned int*)XPT);
  gemm_k<<<dim3(NROW / 128, 4, 4), 256, 0, stream>>>(AP, XPT, C);
  blur_k<<<dim3(256, 512), 256, 0, stream>>>(C, out);
}

// Round 6
// 277.777 us; speedup vs baseline: 28.5454x; 2.0945x over previous
//
#include <hip/hip_runtime.h>
#include <hip/hip_bf16.h>

#define ICN 512
#define OCN 512
#define RS    136      // padded pixel-plane row stride (cols)
#define NROW  17792    // GEMM N = 139*128 >= 130*136=17680; also C plane stride
#define GUARD 144      // zero guard rows in front of XPT (max shift 137)
#define XROWS 17936    // GUARD + NROW

typedef __attribute__((ext_vector_type(8))) short short8;
typedef __attribute__((ext_vector_type(4))) float f32x4;

__device__ __forceinline__ void gload_lds16(const void* g, void* l) {
  __builtin_amdgcn_global_load_lds(
      (const __attribute__((address_space(1))) void*)g,
      (__attribute__((address_space(3))) void*)l, 16, 0, 0);
}

// ---- fused demod + weight pack: AP[tp][oc][ic] = coef[oc]*w[oc][ic][widx(tp)] ----
__global__ __launch_bounds__(256) void wprep_k(const float* __restrict__ w,
                                               __hip_bfloat16* __restrict__ AP) {
  constexpr int WIDX[9] = {0, 2, 6, 8, 1, 7, 3, 5, 4};  // tap -> ky*3+kx
  const int oc = blockIdx.x;
  const int tid = threadIdx.x, lane = tid & 63, wv = tid >> 6;

  float v[2][9];
  float s = 0.f;
#pragma unroll
  for (int rep = 0; rep < 2; ++rep) {
    const int ic = tid + rep * 256;
    const float* wp = w + ((size_t)oc * ICN + ic) * 9;
#pragma unroll
    for (int j = 0; j < 9; ++j) { v[rep][j] = wp[j]; s += wp[j] * wp[j]; }
  }
#pragma unroll
  for (int o = 32; o > 0; o >>= 1) s += __shfl_down(s, o, 64);
  __shared__ float red[4];
  if (lane == 0) red[wv] = s;
  __syncthreads();
  const float tot = red[0] + red[1] + red[2] + red[3];
  const float scale2 = 1.0f / 4608.0f;
  const float c = sqrtf(scale2) * rsqrtf(scale2 * tot + 1e-8f);

#pragma unroll
  for (int rep = 0; rep < 2; ++rep) {
    const int ic = tid + rep * 256;
#pragma unroll
    for (int tp = 0; tp < 9; ++tp)
      AP[((size_t)tp * OCN + oc) * ICN + ic] = __float2bfloat16(c * v[rep][WIDX[tp]]);
  }
}

// ---- x -> bf16 transposed padded pixel space: XPT[row][ic], row = GUARD + py*RS + px
__global__ __launch_bounds__(256) void packx_k(const float* __restrict__ x,
                                               unsigned int* __restrict__ XP32) {
  const int tid = threadIdx.x;
  int row = blockIdx.x * 16;
  for (int r = 0; r < 16; ++r, ++row) {
    float v0 = 0.f, v1 = 0.f;
    if (row >= GUARD) {
      const int p = row - GUARD;           // 0..NROW-1
      const int py = p / RS, px = p - py * RS;
      const int yy = py - 1, xx = px - 1;
      if (yy >= 0 && yy < 128 && xx >= 0 && xx < 128) {
        const int o = yy * 128 + xx;
        v0 = x[(size_t)(2 * tid) * 16384 + o];
        v1 = x[(size_t)(2 * tid + 1) * 16384 + o];
      }
    }
    union { __hip_bfloat16 h[2]; unsigned int u; } cv;
    cv.h[0] = __float2bfloat16(v0);
    cv.h[1] = __float2bfloat16(v1);
    XP32[(size_t)row * 256 + tid] = cv.u;
  }
}

// ---- MFMA implicit GEMM: C[ph][oc][n] = sum_t sum_ic AP[tp][oc][ic]*XPT[n-sh][ic]
// Epilogue writes 0 to pixel-space pad cells so the blur can read branch-free.
__global__ __launch_bounds__(256) void gemm_k(const __hip_bfloat16* __restrict__ AP,
                                              const __hip_bfloat16* __restrict__ XPT,
                                              __hip_bfloat16* __restrict__ C) {
  constexpr int NTt[4]   = {4, 2, 2, 1};
  constexpr int TPO[4]   = {0, 4, 6, 8};
  constexpr int SHIFT[9] = {0, 1, 136, 137, 0, 136, 0, 1, 0};
  constexpr int AR[4]    = {129, 129, 128, 128};  // valid pixel rows per phase
  constexpr int AC[4]    = {129, 128, 129, 128};  // valid pixel cols per phase

  const int n0 = blockIdx.x * 128, oc0 = blockIdx.y * 128, ph = blockIdx.z;
  const int tid = threadIdx.x, lane = tid & 63, wv = tid >> 6;
  const int wr = wv >> 1, wc = wv & 1;

  __shared__ __align__(16) __hip_bfloat16 lA[128 * 32];
  __shared__ __align__(16) __hip_bfloat16 lB[128 * 32];

  const int srow = tid >> 2;          // 0..63 (staging row)
  const int scol = (tid & 3) * 8;     // staging col (elems)
  __hip_bfloat16* ldA0 = &lA[wv * 512];
  __hip_bfloat16* ldA1 = &lA[wv * 512 + 2048];
  __hip_bfloat16* ldB0 = &lB[wv * 512];
  __hip_bfloat16* ldB1 = &lB[wv * 512 + 2048];

  f32x4 acc[4][4];
#pragma unroll
  for (int m = 0; m < 4; ++m)
#pragma unroll
    for (int n = 0; n < 4; ++n) acc[m][n] = (f32x4){0.f, 0.f, 0.f, 0.f};

  const int ntaps = NTt[ph];
  for (int t = 0; t < ntaps; ++t) {
    const int tp = TPO[ph] + t;
    const __hip_bfloat16* Ab = AP + (size_t)tp * (ICN * OCN) + (size_t)oc0 * ICN;
    const __hip_bfloat16* Bb = XPT + (size_t)(GUARD + n0 - SHIFT[tp]) * ICN;
    for (int ks = 0; ks < 16; ++ks) {
      const int kc = ks * 32 + scol;
      gload_lds16(Ab + (size_t)srow * ICN + kc, ldA0);
      gload_lds16(Ab + (size_t)(srow + 64) * ICN + kc, ldA1);
      gload_lds16(Bb + (size_t)srow * ICN + kc, ldB0);
      gload_lds16(Bb + (size_t)(srow + 64) * ICN + kc, ldB1);
      __syncthreads();
      short8 af[4], bfr[4];
#pragma unroll
      for (int m = 0; m < 4; ++m)
        af[m] = *(const short8*)&lA[(wr * 64 + m * 16 + (lane & 15)) * 32 + (lane >> 4) * 8];
#pragma unroll
      for (int n = 0; n < 4; ++n)
        bfr[n] = *(const short8*)&lB[(wc * 64 + n * 16 + (lane & 15)) * 32 + (lane >> 4) * 8];
#pragma unroll
      for (int m = 0; m < 4; ++m)
#pragma unroll
        for (int n = 0; n < 4; ++n)
          acc[m][n] = __builtin_amdgcn_mfma_f32_16x16x32_bf16(af[m], bfr[n], acc[m][n], 0, 0, 0);
      __syncthreads();
    }
  }

  // epilogue: D col = lane&15, row = (lane>>4)*4 + r; mask pad cells to zero
  const int lr = (lane >> 4) * 4, lc = lane & 15;
#pragma unroll
  for (int n = 0; n < 4; ++n) {
    const int col = n0 + wc * 64 + n * 16 + lc;
    const int pa = col / 136, pb = col - pa * 136;
    const bool ok = ((unsigned)(pa - 1) < (unsigned)AR[ph]) &&
                    ((unsigned)(pb - 1) < (unsigned)AC[ph]);
#pragma unroll
    for (int m = 0; m < 4; ++m)
#pragma unroll
      for (int r = 0; r < 4; ++r) {
        const int row = oc0 + wr * 64 + m * 16 + lr + r;
        C[((size_t)(ph * OCN + row)) * NROW + col] =
            __float2bfloat16(ok ? acc[m][n][r] : 0.f);
      }
  }
}

// ---- vectorized depthwise 4x4 blur: 8 outputs/thread, branch-free ----
// Requires C pad cells == 0 (provided by gemm_k's masked epilogue).
struct __align__(8) U4 { unsigned int w[4]; };

__global__ __launch_bounds__(256) void blur2_k(const unsigned short* __restrict__ C,
                                               float* __restrict__ out) {
  const int tid = threadIdx.x;
  const int t  = tid & 31;                  // col block: n in [8t, 8t+8)
  const int m  = blockIdx.x * 8 + (tid >> 5);
  const int oc = blockIdx.y;
  const float cfv[4] = {0.25f, 0.75f, 0.75f, 0.25f};

  float acc[8];
#pragma unroll
  for (int s = 0; s < 8; ++s) acc[s] = 0.f;

#pragma unroll
  for (int i = 0; i < 4; ++i) {
    const int u  = m - 1 + i;
    const int py = u & 1;                   // u=-1 -> 1; u=257 -> 1
    const int r  = (u >> 1) + 1;            // u=-1 -> 0 (zero pad row)
    const size_t base = (size_t)r * 136 + 4 * t;
    const U4 ev = *(const U4*)(C + ((size_t)(py * 2 + 0) * OCN + oc) * NROW + base);
    const U4 ov = *(const U4*)(C + ((size_t)(py * 2 + 1) * OCN + oc) * NROW + base);
    float E[8], O[8];
#pragma unroll
    for (int j = 0; j < 4; ++j) {
      E[2 * j]     = __uint_as_float(ev.w[j] << 16);
      E[2 * j + 1] = __uint_as_float(ev.w[j] & 0xffff0000u);
      O[2 * j]     = __uint_as_float(ov.w[j] << 16);
      O[2 * j + 1] = __uint_as_float(ov.w[j] & 0xffff0000u);
    }
    const float cv = cfv[i];
#pragma unroll
    for (int s = 0; s < 8; ++s) {
      float h;
      if ((s & 1) == 0) {
        const int k = s >> 1;
        h = 0.75f * E[k + 1] + 0.25f * E[k + 2] + 0.25f * O[k] + 0.75f * O[k + 1];
      } else {
        const int k = (s + 1) >> 1;
        h = 0.25f * E[k] + 0.75f * E[k + 1] + 0.75f * O[k] + 0.25f * O[k + 1];
      }
      acc[s] += cv * h;
    }
  }

  float* op = out + ((size_t)oc * 256 + m) * 256 + 8 * t;
  f32x4 s0 = {acc[0], acc[1], acc[2], acc[3]};
  f32x4 s1 = {acc[4], acc[5], acc[6], acc[7]};
  *(f32x4*)op = s0;
  *(f32x4*)(op + 4) = s1;
}

extern "C" void kernel_launch(void* const* d_in, const int* in_sizes, int n_in,
                              void* d_out, int out_size, void* d_ws, size_t ws_size,
                              hipStream_t stream) {
  const float* x = (const float*)d_in[0];
  const float* w = (const float*)d_in[1];
  float* out = (float*)d_out;

  // ws layout (bytes):
  //   AP : 9*512*512*2   = 4,718,592    @ 0
  //   XPT: 17936*512*2   = 18,366,464   @ 4,718,592
  //   C  : 4*512*17792*2 = 72,876,032   @ 23,085,056   (total ~96.0 MB)
  __hip_bfloat16* AP  = (__hip_bfloat16*)d_ws;
  __hip_bfloat16* XPT = (__hip_bfloat16*)((char*)d_ws + 4718592);
  __hip_bfloat16* C   = (__hip_bfloat16*)((char*)d_ws + 23085056);

  wprep_k<<<512, 256, 0, stream>>>(w, AP);
  packx_k<<<XROWS / 16, 256, 0, stream>>>(x, (unsigned int*)XPT);
  gemm_k<<<dim3(NROW / 128, 4, 4), 256, 0, stream>>>(AP, XPT, C);
  blur2_k<<<dim3(32, 512), 256, 0, stream>>>((const unsigned short*)C, out);
}

// Round 7
// 173.109 us; speedup vs baseline: 45.8050x; 1.6046x over previous
//
#include <hip/hip_runtime.h>
#include <hip/hip_bf16.h>

#define ICN 512
#define OCN 512
#define RS    136      // padded pixel-plane row stride (cols)
#define NROW  17792    // GEMM N = 139*128 >= 130*136=17680; also C plane stride
#define GUARD 144      // zero guard rows in front of XPT (max shift 137)
#define XROWS 17936    // GUARD + NROW

typedef __attribute__((ext_vector_type(8))) short short8;
typedef __attribute__((ext_vector_type(4))) float f32x4;

__device__ __forceinline__ void gload_lds16(const void* g, void* l) {
  __builtin_amdgcn_global_load_lds(
      (const __attribute__((address_space(1))) void*)g,
      (__attribute__((address_space(3))) void*)l, 16, 0, 0);
}

// ---- fused demod + weight pack: AP[tp][oc][ic] = coef[oc]*w[oc][ic][widx(tp)] ----
__global__ __launch_bounds__(256) void wprep_k(const float* __restrict__ w,
                                               __hip_bfloat16* __restrict__ AP) {
  constexpr int WIDX[9] = {0, 2, 6, 8, 1, 7, 3, 5, 4};  // tap -> ky*3+kx
  const int oc = blockIdx.x;
  const int tid = threadIdx.x, lane = tid & 63, wv = tid >> 6;

  float v[2][9];
  float s = 0.f;
#pragma unroll
  for (int rep = 0; rep < 2; ++rep) {
    const int ic = tid + rep * 256;
    const float* wp = w + ((size_t)oc * ICN + ic) * 9;
#pragma unroll
    for (int j = 0; j < 9; ++j) { v[rep][j] = wp[j]; s += wp[j] * wp[j]; }
  }
#pragma unroll
  for (int o = 32; o > 0; o >>= 1) s += __shfl_down(s, o, 64);
  __shared__ float red[4];
  if (lane == 0) red[wv] = s;
  __syncthreads();
  const float tot = red[0] + red[1] + red[2] + red[3];
  const float scale2 = 1.0f / 4608.0f;
  const float c = sqrtf(scale2) * rsqrtf(scale2 * tot + 1e-8f);

#pragma unroll
  for (int rep = 0; rep < 2; ++rep) {
    const int ic = tid + rep * 256;
#pragma unroll
    for (int tp = 0; tp < 9; ++tp)
      AP[((size_t)tp * OCN + oc) * ICN + ic] = __float2bfloat16(c * v[rep][WIDX[tp]]);
  }
}

// ---- x -> bf16 transposed padded pixel space, via LDS transpose tile ----
// XPT[row][ic], row = GUARD + py*136 + px; valid pixels px-1,py-1 in [0,128)
__global__ __launch_bounds__(256) void packx2_k(const float* __restrict__ x,
                                                unsigned int* __restrict__ XP32) {
  const int py  = blockIdx.x;        // 0..129
  const int ic0 = blockIdx.y * 64;
  const int tid = threadIdx.x;
  const int yy  = py - 1;
  const bool rowvalid = (unsigned)yy < 128u;

  __shared__ __hip_bfloat16 T[128 * 65];   // T[xx][ic_i], padded stride 65

  if (rowvalid) {
    const float4* xr = (const float4*)(x + (size_t)ic0 * 16384 + (size_t)yy * 128);
#pragma unroll
    for (int rep = 0; rep < 8; ++rep) {
      const int idx = rep * 256 + tid;     // 0..2047
      const int x4 = idx & 31, ici = idx >> 5;
      const float4 v = xr[(size_t)ici * 4096 + x4];   // coalesced 16B/lane
      const int xx = x4 * 4;
      T[(xx + 0) * 65 + ici] = __float2bfloat16(v.x);
      T[(xx + 1) * 65 + ici] = __float2bfloat16(v.y);
      T[(xx + 2) * 65 + ici] = __float2bfloat16(v.z);
      T[(xx + 3) * 65 + ici] = __float2bfloat16(v.w);
    }
  }
  __syncthreads();

  const size_t rowbase = (size_t)(GUARD + py * 136) * 256 + (ic0 >> 1);
  // 136 px-rows * 32 u32 = 4352 words; 17 reps of 256
  for (int rep = 0; rep < 17; ++rep) {
    const int idx = rep * 256 + tid;
    const int px = idx >> 5, j = idx & 31;
    unsigned int uv = 0;
    if (rowvalid && (unsigned)(px - 1) < 128u) {
      union { __hip_bfloat16 h[2]; unsigned int u; } cv;
      cv.h[0] = T[(px - 1) * 65 + 2 * j];
      cv.h[1] = T[(px - 1) * 65 + 2 * j + 1];
      uv = cv.u;
    }
    XP32[rowbase + (size_t)px * 256 + j] = uv;   // coalesced 128B/half-wave
  }
}

// ---- zero the guard rows [0,144) and tail rows [17824,17936) of XPT ----
__global__ __launch_bounds__(256) void zguard_k(unsigned int* __restrict__ XP32) {
  const int r = blockIdx.x;                       // 0..255
  const int row = (r < 144) ? r : (r + 17680);    // 144->17824 .. 255->17935
  XP32[(size_t)row * 256 + threadIdx.x] = 0;
}

// ---- MFMA implicit GEMM: C[ph][oc][n] = sum_t sum_ic AP[tp][oc][ic]*XPT[n-sh][ic]
// Epilogue writes 0 to pixel-space pad cells so the blur can read branch-free.
__global__ __launch_bounds__(256) void gemm_k(const __hip_bfloat16* __restrict__ AP,
                                              const __hip_bfloat16* __restrict__ XPT,
                                              __hip_bfloat16* __restrict__ C) {
  constexpr int NTt[4]   = {4, 2, 2, 1};
  constexpr int TPO[4]   = {0, 4, 6, 8};
  constexpr int SHIFT[9] = {0, 1, 136, 137, 0, 136, 0, 1, 0};
  constexpr int AR[4]    = {129, 129, 128, 128};  // valid pixel rows per phase
  constexpr int AC[4]    = {129, 128, 129, 128};  // valid pixel cols per phase

  const int n0 = blockIdx.x * 128, oc0 = blockIdx.y * 128, ph = blockIdx.z;
  const int tid = threadIdx.x, lane = tid & 63, wv = tid >> 6;
  const int wr = wv >> 1, wc = wv & 1;

  __shared__ __align__(16) __hip_bfloat16 lA[128 * 32];
  __shared__ __align__(16) __hip_bfloat16 lB[128 * 32];

  const int srow = tid >> 2;          // 0..63 (staging row)
  const int scol = (tid & 3) * 8;     // staging col (elems)
  __hip_bfloat16* ldA0 = &lA[wv * 512];
  __hip_bfloat16* ldA1 = &lA[wv * 512 + 2048];
  __hip_bfloat16* ldB0 = &lB[wv * 512];
  __hip_bfloat16* ldB1 = &lB[wv * 512 + 2048];

  f32x4 acc[4][4];
#pragma unroll
  for (int m = 0; m < 4; ++m)
#pragma unroll
    for (int n = 0; n < 4; ++n) acc[m][n] = (f32x4){0.f, 0.f, 0.f, 0.f};

  const int ntaps = NTt[ph];
  for (int t = 0; t < ntaps; ++t) {
    const int tp = TPO[ph] + t;
    const __hip_bfloat16* Ab = AP + (size_t)tp * (ICN * OCN) + (size_t)oc0 * ICN;
    const __hip_bfloat16* Bb = XPT + (size_t)(GUARD + n0 - SHIFT[tp]) * ICN;
    for (int ks = 0; ks < 16; ++ks) {
      const int kc = ks * 32 + scol;
      gload_lds16(Ab + (size_t)srow * ICN + kc, ldA0);
      gload_lds16(Ab + (size_t)(srow + 64) * ICN + kc, ldA1);
      gload_lds16(Bb + (size_t)srow * ICN + kc, ldB0);
      gload_lds16(Bb + (size_t)(srow + 64) * ICN + kc, ldB1);
      __syncthreads();
      short8 af[4], bfr[4];
#pragma unroll
      for (int m = 0; m < 4; ++m)
        af[m] = *(const short8*)&lA[(wr * 64 + m * 16 + (lane & 15)) * 32 + (lane >> 4) * 8];
#pragma unroll
      for (int n = 0; n < 4; ++n)
        bfr[n] = *(const short8*)&lB[(wc * 64 + n * 16 + (lane & 15)) * 32 + (lane >> 4) * 8];
#pragma unroll
      for (int m = 0; m < 4; ++m)
#pragma unroll
        for (int n = 0; n < 4; ++n)
          acc[m][n] = __builtin_amdgcn_mfma_f32_16x16x32_bf16(af[m], bfr[n], acc[m][n], 0, 0, 0);
      __syncthreads();
    }
  }

  // epilogue: D col = lane&15, row = (lane>>4)*4 + r; mask pad cells to zero
  const int lr = (lane >> 4) * 4, lc = lane & 15;
#pragma unroll
  for (int n = 0; n < 4; ++n) {
    const int col = n0 + wc * 64 + n * 16 + lc;
    const int pa = col / 136, pb = col - pa * 136;
    const bool ok = ((unsigned)(pa - 1) < (unsigned)AR[ph]) &&
                    ((unsigned)(pb - 1) < (unsigned)AC[ph]);
#pragma unroll
    for (int m = 0; m < 4; ++m)
#pragma unroll
      for (int r = 0; r < 4; ++r) {
        const int row = oc0 + wr * 64 + m * 16 + lr + r;
        C[((size_t)(ph * OCN + row)) * NROW + col] =
            __float2bfloat16(ok ? acc[m][n][r] : 0.f);
      }
  }
}

// ---- vectorized depthwise 4x4 blur: 8 outputs/thread, branch-free ----
// Requires C pad cells == 0 (provided by gemm_k's masked epilogue).
struct __align__(8) U4 { unsigned int w[4]; };

__global__ __launch_bounds__(256) void blur2_k(const unsigned short* __restrict__ C,
                                               float* __restrict__ out) {
  const int tid = threadIdx.x;
  const int t  = tid & 31;                  // col block: n in [8t, 8t+8)
  const int m  = blockIdx.x * 8 + (tid >> 5);
  const int oc = blockIdx.y;
  const float cfv[4] = {0.25f, 0.75f, 0.75f, 0.25f};

  float acc[8];
#pragma unroll
  for (int s = 0; s < 8; ++s) acc[s] = 0.f;

#pragma unroll
  for (int i = 0; i < 4; ++i) {
    const int u  = m - 1 + i;
    const int py = u & 1;                   // u=-1 -> 1; u=257 -> 1
    const int r  = (u >> 1) + 1;            // u=-1 -> 0 (zero pad row)
    const size_t base = (size_t)r * 136 + 4 * t;
    const U4 ev = *(const U4*)(C + ((size_t)(py * 2 + 0) * OCN + oc) * NROW + base);
    const U4 ov = *(const U4*)(C + ((size_t)(py * 2 + 1) * OCN + oc) * NROW + base);
    float E[8], O[8];
#pragma unroll
    for (int j = 0; j < 4; ++j) {
      E[2 * j]     = __uint_as_float(ev.w[j] << 16);
      E[2 * j + 1] = __uint_as_float(ev.w[j] & 0xffff0000u);
      O[2 * j]     = __uint_as_float(ov.w[j] << 16);
      O[2 * j + 1] = __uint_as_float(ov.w[j] & 0xffff0000u);
    }
    const float cv = cfv[i];
#pragma unroll
    for (int s = 0; s < 8; ++s) {
      float h;
      if ((s & 1) == 0) {
        const int k = s >> 1;
        h = 0.75f * E[k + 1] + 0.25f * E[k + 2] + 0.25f * O[k] + 0.75f * O[k + 1];
      } else {
        const int k = (s + 1) >> 1;
        h = 0.25f * E[k] + 0.75f * E[k + 1] + 0.75f * O[k] + 0.25f * O[k + 1];
      }
      acc[s] += cv * h;
    }
  }

  float* op = out + ((size_t)oc * 256 + m) * 256 + 8 * t;
  f32x4 s0 = {acc[0], acc[1], acc[2], acc[3]};
  f32x4 s1 = {acc[4], acc[5], acc[6], acc[7]};
  *(f32x4*)op = s0;
  *(f32x4*)(op + 4) = s1;
}

extern "C" void kernel_launch(void* const* d_in, const int* in_sizes, int n_in,
                              void* d_out, int out_size, void* d_ws, size_t ws_size,
                              hipStream_t stream) {
  const float* x = (const float*)d_in[0];
  const float* w = (const float*)d_in[1];
  float* out = (float*)d_out;

  // ws layout (bytes):
  //   AP : 9*512*512*2   = 4,718,592    @ 0
  //   XPT: 17936*512*2   = 18,366,464   @ 4,718,592
  //   C  : 4*512*17792*2 = 72,876,032   @ 23,085,056   (total ~96.0 MB)
  __hip_bfloat16* AP  = (__hip_bfloat16*)d_ws;
  __hip_bfloat16* XPT = (__hip_bfloat16*)((char*)d_ws + 4718592);
  __hip_bfloat16* C   = (__hip_bfloat16*)((char*)d_ws + 23085056);

  wprep_k<<<512, 256, 0, stream>>>(w, AP);
  zguard_k<<<256, 256, 0, stream>>>((unsigned int*)XPT);
  packx2_k<<<dim3(130, 8), 256, 0, stream>>>(x, (unsigned int*)XPT);
  gemm_k<<<dim3(NROW / 128, 4, 4), 256, 0, stream>>>(AP, XPT, C);
  blur2_k<<<dim3(32, 512), 256, 0, stream>>>((const unsigned short*)C, out);
}